// Round 11
// baseline (148.183 us; speedup 1.0000x reference)
//
#include <hip/hip_runtime.h>

// ---------------------------------------------------------------------------
// MapEncoder, round 11: identical to round 10 EXCEPT __launch_bounds__ of
// enc_mfma changed (1024,8) -> (1024,4). R10's min-8-waves hint made the
// register allocator clamp to 32 VGPRs and spill accumulators to scratch
// (WRITE_SIZE 8MB -> 119MB, enc 90 -> 118us). Occupancy (2 blocks/CU,
// 8 waves/SIMD) is enforced by LDS (74.75KB) regardless of the hint.
// Fragment convention (HW-verified m89/m91): lane&15 = N index, 8 contiguous
// k per lane at k-group (lane>>4)*8; D: col=lane&15, row=4*(lane>>4)+reg.
// ---------------------------------------------------------------------------

#define NPOLY 16384
#define NPB   4
#define NC    80
#define NT    5

typedef float f32x4  __attribute__((ext_vector_type(4)));
typedef short bf16x8 __attribute__((ext_vector_type(8)));

__device__ __forceinline__ unsigned short f2bf(float x) {
    union { float f; unsigned u; } v; v.f = x;
    unsigned r = v.u + 0x7FFF + ((v.u >> 16) & 1);
    return (unsigned short)(r >> 16);
}
__device__ __forceinline__ float bf2f(unsigned short s) {
    union { unsigned u; float f; } v; v.u = ((unsigned)s) << 16;
    return v.f;
}
__device__ __forceinline__ unsigned cvtpk(float a, float b) {
    unsigned r;
    asm("v_cvt_pk_bf16_f32 %0, %1, %2" : "=v"(r) : "v"(a), "v"(b));
    return r;
}
__device__ __forceinline__ float bflo(unsigned u) {
    union { unsigned x; float f; } w; w.x = u << 16; return w.f;
}
__device__ __forceinline__ float bfhi(unsigned u) {
    union { unsigned x; float f; } w; w.x = u & 0xFFFF0000u; return w.f;
}

// ---- workspace layout (bytes) ----
#define WS_CNT  0
#define WS_LIST 64         // u16 list[16384]
#define WS_W2   33792      // 64 frags  (A-style, M=256 K=128)
#define WS_W3   99328      // 256 frags (A-style, M=256 K=512) — PRE-SCALED by sc2
#define WS_W4   361472     // 128 frags (B-style, N=256 K=256)
#define WS_WP1  492544     // 256 frags (A-style, M=512 K=256)
#define WS_WP2  754688     // 256 frags (B-style, N=256 K=512)

// ---- enc LDS layout (dynamic, bytes) ----
#define L_CAT   0          // 40 frags h B-operand; overlays feat (P0/P1), runs (P5/P6)
#define L_H1    40960      // 20 frags h1 B-op; later h2c A-frags
#define L_H2C   40960
#define L_PFRAG 61440      // 8 frags pooled B-operand
#define L_APOF  69632      // f32[4][256]: pooled@W3' + (b3-m2)*sc2 + be2
#define L_OF    73728      // f32[256]
#define L_TOT   74752

// ---------------------------------------------------------------------------
// prep_all: bid<960 -> weight frag prep (W3 scaled by sc2);
//           bid>=960 -> mask norm/compaction + out2 + zero inactive out0 rows.
// ---------------------------------------------------------------------------
__global__ __launch_bounds__(512) void prep_all(
    const float* __restrict__ W2, const float* __restrict__ W3,
    const float* __restrict__ W4, const float* __restrict__ Wp1,
    const float* __restrict__ Wp2, const float* __restrict__ g2,
    const float* __restrict__ v2, const unsigned char* __restrict__ mraw,
    unsigned short* __restrict__ wsu, float* __restrict__ out2,
    unsigned short* __restrict__ list, int* __restrict__ cnt,
    float* __restrict__ out0)
{
    const int bid = blockIdx.x;
    const int tid = threadIdx.x;
    if (bid < 960) {
        const float* src; int mode, KS, ld, fid; size_t dst; bool scl = false;
        if      (bid < 64)  { src = W2;  mode = 0; KS = 0; ld = 256; fid = bid;       dst = WS_W2;  }
        else if (bid < 320) { src = W3;  mode = 1; KS = 4; ld = 256; fid = bid - 64;  dst = WS_W3; scl = true; }
        else if (bid < 448) { src = W4;  mode = 2; KS = 0; ld = 256; fid = bid - 320; dst = WS_W4;  }
        else if (bid < 704) { src = Wp1; mode = 1; KS = 2; ld = 512; fid = bid - 448; dst = WS_WP1; }
        else                { src = Wp2; mode = 2; KS = 0; ld = 256; fid = bid - 704; dst = WS_WP2; }

        int mt, kt;
        if (mode == 0) { mt = fid & 15; kt = fid >> 4; }
        else if (mode == 1) {
            const int low = fid & 15, hi = fid >> 4;
            mt = (hi / KS) * 4 + (low >> 2);
            kt = (hi % KS) * 4 + (low & 3);
        } else {
            const int low = fid & 31;
            kt = (fid >> 5) * 2 + (low & 1);
            mt = ((low >> 4) & 1) * 8 + ((low >> 1) & 7);
        }
        const int l15 = tid & 15, e = (tid >> 4) & 7, lg = (tid >> 7) & 3;
        const int m = mt * 16 + l15;
        const int k = kt * 32 + lg * 8 + e;
        float val = src[(size_t)k * ld + m];
        if (scl) val *= rsqrtf(v2[m] + 1e-5f) * g2[m];
        wsu[dst / 2 + (size_t)fid * 512 + (l15 + 16 * lg) * 8 + e] = f2bf(val);
    } else {
        __shared__ int s_nz;
        __shared__ unsigned char s_v[256];
        const int mb = bid - 960;
        if (tid == 0) s_nz = 0;
        __syncthreads();
        int local = 0;
        if (tid < 256) {
            for (int j = 0; j < 64; j++) {
                const int i = tid * 64 + j;           // scan first 16KB
                if ((i & 3) != 0) local |= mraw[i];
            }
        }
        if (local) atomicOr(&s_nz, 1);
        __syncthreads();
        const bool isByte = (s_nz != 0);
        if (tid < 256) {
            const int i = mb * 256 + tid;
            const unsigned char v = isByte ? (mraw[i] != 0) : (((const int*)mraw)[i] != 0);
            out2[i] = v ? 0.0f : 1.0f;
            s_v[tid] = v;
            if (v) { const int pos = atomicAdd(cnt, 1); list[pos] = (unsigned short)i; }
        }
        __syncthreads();
        const float4 z = {0.f, 0.f, 0.f, 0.f};
        for (int rr = 0; rr < 32; rr++) {
            const int row = rr * 8 + (tid >> 6);
            if (!s_v[row]) {
                const size_t go = (size_t)(mb * 256 + row) * 256;
                ((float4*)(out0 + go))[tid & 63] = z;
            }
        }
    }
}

// ---------------------------------------------------------------------------
// main encoder: 1024 threads = 16 waves, NPB=4, ~73 KB LDS, 2 blocks/CU,
// 8 waves/SIMD (LDS-enforced). Wave (mw = wid&7, nw = wid>>3).
// ---------------------------------------------------------------------------
__global__ __launch_bounds__(1024, 4) void enc_mfma(
    const float* __restrict__ tgt, const int* __restrict__ label,
    const unsigned short* __restrict__ list, const int* __restrict__ cnt,
    const float* __restrict__ W1, const float* __restrict__ b1,
    const float* __restrict__ g1, const float* __restrict__ be1,
    const float* __restrict__ m1, const float* __restrict__ v1,
    const float* __restrict__ b2, const float* __restrict__ b3,
    const float* __restrict__ g2, const float* __restrict__ be2,
    const float* __restrict__ m2, const float* __restrict__ v2,
    const float* __restrict__ b4, const float* __restrict__ temb,
    const char* __restrict__ wsb, float* __restrict__ out0)
{
    extern __shared__ char smem[];
    const int nact  = cnt[0];
    const int bbase = blockIdx.x * NPB;
    if (bbase >= nact) return;

    const int tid  = threadIdx.x;
    const int wid  = tid >> 6;
    const int lane = tid & 63;
    const int l15  = lane & 15, lg = lane >> 4;
    const int mw   = wid & 7,  nw = wid >> 3;
    const int nj0  = nw ? 3 : 0;
    const int njc  = nw ? 2 : 3;

    // ---------- P0: feat (CAT overlay, 36B rows) + OF vector ----------
    if (tid < NC) {
        const int c = tid, pl = c / 20, p = c - pl * 20;
        const int gpoly = list[min(bbase + pl, nact - 1)];
        const size_t gp = (size_t)gpoly * 42;
        const float px = tgt[gp + p * 2],     py = tgt[gp + p * 2 + 1];
        const float qx = tgt[gp + p * 2 + 2], qy = tgt[gp + p * 2 + 3];
        const float cx = tgt[gp + 20],        cy = tgt[gp + 21];
        const float vx = qx - px, vy = qy - py;
        const float inv = 1.0f / (sqrtf(vx * vx + vy * vy) + 1.0f + 1e-6f);
        float* f = (float*)(smem + L_CAT + c * 36);
        f[0] = px - cx; f[1] = py - cy; f[2] = vx; f[3] = vy;
        f[4] = vx * inv; f[5] = vy * inv;
    }
    if (tid < 256) {
        const float sc = rsqrtf(v2[tid] + 1e-5f) * g2[tid];
        ((float*)(smem + L_OF))[tid] = (b3[tid] - m2[tid]) * sc + be2[tid];
    }
    __syncthreads();

    // ---------- P1: h1 = relu(bn1(feat@W1+b1)) -> B-frags ----------
    {
        const int ch = tid & 127, cblk = tid >> 7;      // 8 col-groups of 10
        float w[6];
        #pragma unroll
        for (int j = 0; j < 6; j++) w[j] = W1[j * 128 + ch];
        const float sc1  = rsqrtf(v1[ch] + 1e-5f) * g1[ch];
        const float off1 = (b1[ch] - m1[ch]) * sc1 + be1[ch];
        const int kt = ch >> 5, koff = ch & 31;
        const int lane16 = 16 * (koff >> 3);
        #pragma unroll 2
        for (int i = 0; i < 10; i++) {
            const int c = i * 8 + cblk;
            const float* f = (const float*)(smem + L_CAT + c * 36);
            float a = 0.f;
            #pragma unroll
            for (int j = 0; j < 6; j++) a = fmaf(f[j], w[j], a);
            a = fmaxf(fmaf(a, sc1, off1), 0.0f);
            *(unsigned short*)(smem + L_H1 + (kt * NT + (c >> 4)) * 1024 +
                               ((c & 15) + lane16) * 16 + (koff & 7) * 2) = f2bf(a);
        }
    }
    __syncthreads();

    // ---------- S3: h^T = W2^T @ h1^T (wave = 2 mt x its nj-set) ----------
    {
        f32x4 acc[2][3];
        #pragma unroll
        for (int a = 0; a < 2; a++)
            #pragma unroll
            for (int b = 0; b < 3; b++) acc[a][b] = (f32x4){0.f, 0.f, 0.f, 0.f};

        #pragma unroll
        for (int kt = 0; kt < 4; kt++) {
            bf16x8 a0 = *(const bf16x8*)(wsb + WS_W2 + (size_t)(kt * 16 + mw * 2 + 0) * 1024 + lane * 16);
            bf16x8 a1 = *(const bf16x8*)(wsb + WS_W2 + (size_t)(kt * 16 + mw * 2 + 1) * 1024 + lane * 16);
            #pragma unroll
            for (int j = 0; j < 3; j++) {
                if (j < njc) {
                    const bf16x8 bb = *(const bf16x8*)(smem + L_H1 + (kt * NT + nj0 + j) * 1024 + lane * 16);
                    acc[0][j] = __builtin_amdgcn_mfma_f32_16x16x32_bf16(a0, bb, acc[0][j], 0, 0, 0);
                    acc[1][j] = __builtin_amdgcn_mfma_f32_16x16x32_bf16(a1, bb, acc[1][j], 0, 0, 0);
                }
            }
        }
        #pragma unroll
        for (int mi = 0; mi < 2; mi++) {
            const int mt = mw * 2 + mi, chb = mt * 16 + lg * 4;
            const float4 bv = *(const float4*)(b2 + chb);
            const int kt = chb >> 5, koff = chb & 31;
            const int lane16 = l15 + 16 * (koff >> 3);
            #pragma unroll
            for (int j = 0; j < 3; j++) {
                if (j < njc) {
                    const f32x4 v = acc[mi][j];
                    uint2 pk;
                    pk.x = cvtpk(v[0] + bv.x, v[1] + bv.y);
                    pk.y = cvtpk(v[2] + bv.z, v[3] + bv.w);
                    *(uint2*)(smem + L_CAT + (kt * NT + nj0 + j) * 1024 + lane16 * 16 + (koff & 7) * 2) = pk;
                }
            }
        }
    }
    __syncthreads();

    // ---------- P3: pooled = max_p h -> PFRAG B-frags ----------
    if (tid < 128) {
        const int pl = tid >> 5, grp = tid & 31;
        const int fragbase = (grp >> 2) * NT;
        const int off16 = 16 * (grp & 3);
        float mx[8];
        #pragma unroll
        for (int e = 0; e < 8; e++) mx[e] = -3.0e38f;
        #pragma unroll 4
        for (int p = 0; p < 20; p++) {
            int pp = p + grp;
            pp -= (pp >= 40) ? 40 : ((pp >= 20) ? 20 : 0);
            const int c = pl * 20 + pp;
            const uint4 v = *(const uint4*)(smem + L_CAT +
                (fragbase + (c >> 4)) * 1024 + ((c & 15) + off16) * 16);
            mx[0] = fmaxf(mx[0], bflo(v.x)); mx[1] = fmaxf(mx[1], bfhi(v.x));
            mx[2] = fmaxf(mx[2], bflo(v.y)); mx[3] = fmaxf(mx[3], bfhi(v.y));
            mx[4] = fmaxf(mx[4], bflo(v.z)); mx[5] = fmaxf(mx[5], bfhi(v.z));
            mx[6] = fmaxf(mx[6], bflo(v.w)); mx[7] = fmaxf(mx[7], bfhi(v.w));
        }
        uint4 pk;
        pk.x = cvtpk(mx[0], mx[1]); pk.y = cvtpk(mx[2], mx[3]);
        pk.z = cvtpk(mx[4], mx[5]); pk.w = cvtpk(mx[6], mx[7]);
        *(uint4*)(smem + L_PFRAG + (grp >> 2) * 1024 + (pl + 16 * (grp & 3)) * 16) = pk;
    }
    __syncthreads();

    // ---------- pooled GEMM: APOF = pooled @ W3'[256:] + OF (wave = 1 mt) --
    {
        f32x4 accp = {0.f, 0.f, 0.f, 0.f};
        #pragma unroll
        for (int kk = 0; kk < 8; kk++) {
            const int kt = 8 + kk;
            const int fid = ((wid >> 2) * 4 + (kt >> 2)) * 16 + (wid & 3) * 4 + (kt & 3);
            const bf16x8 a = *(const bf16x8*)(wsb + WS_W3 + (size_t)fid * 1024 + lane * 16);
            const bf16x8 bb = *(const bf16x8*)(smem + L_PFRAG + kk * 1024 + lane * 16);
            accp = __builtin_amdgcn_mfma_f32_16x16x32_bf16(a, bb, accp, 0, 0, 0);
        }
        if (l15 < 4) {
            const int ch0 = wid * 16 + lg * 4;
            const float4 ofv = *(const float4*)(smem + L_OF + ch0 * 4);
            float4 o;
            o.x = accp[0] + ofv.x; o.y = accp[1] + ofv.y;
            o.z = accp[2] + ofv.z; o.w = accp[3] + ofv.w;
            *(float4*)(smem + L_APOF + l15 * 1024 + ch0 * 4) = o;
        }
    }
    __syncthreads();

    // ---------- P4: 2 chunks of 128 out-ch: S4 (K=256) fused w/ S5 --------
    f32x4 acc5[5];
    #pragma unroll
    for (int a = 0; a < 5; a++) acc5[a] = (f32x4){0.f, 0.f, 0.f, 0.f};

    #pragma unroll 1
    for (int chunk = 0; chunk < 2; chunk++) {
        const int mtg = chunk * 8 + mw;
        f32x4 acc4[3];
        #pragma unroll
        for (int s = 0; s < 3; s++) acc4[s] = (f32x4){0.f, 0.f, 0.f, 0.f};

        #pragma unroll
        for (int ktg = 0; ktg < 8; ktg++) {
            const int fid = ((mtg >> 2) * 4 + (ktg >> 2)) * 16 + (mtg & 3) * 4 + (ktg & 3);
            const bf16x8 a = *(const bf16x8*)(wsb + WS_W3 + (size_t)fid * 1024 + lane * 16);
            #pragma unroll
            for (int j = 0; j < 3; j++) {
                if (j < njc) {
                    const bf16x8 bb = *(const bf16x8*)(smem + L_CAT + (ktg * NT + nj0 + j) * 1024 + lane * 16);
                    acc4[j] = __builtin_amdgcn_mfma_f32_16x16x32_bf16(a, bb, acc4[j], 0, 0, 0);
                }
            }
        }
        // S5 B-frags (W4) for this chunk, wave column ntB = wid
        bf16x8 b5[4];
        #pragma unroll
        for (int kt2 = 0; kt2 < 4; kt2++) {
            const int ktB = chunk * 4 + kt2, ntB = wid;
            const int fid = (ktB >> 1) * 32 + ((ntB >> 3) & 1) * 16 + (ntB & 7) * 2 + (ktB & 1);
            b5[kt2] = *(const bf16x8*)(wsb + WS_W4 + (size_t)fid * 1024 + lane * 16);
        }
        // epilogue: h2 = relu(acc4 + APOF) -> h2c A-frags
        {
            const int choff = mw * 16 + lg * 4;
            const int ch0g = mtg * 16 + lg * 4;
            const int kt2e = choff >> 5;
            const int lane16 = l15 + 16 * ((choff & 31) >> 3);
            const int sub = (lg & 1) * 8;
            #pragma unroll
            for (int j = 0; j < 3; j++) {
                if (j < njc) {
                    const int nj = nj0 + j;
                    const float4 ofv = *(const float4*)(smem + L_APOF +
                        (unsigned)((nj * 16 + l15) / 20) * 1024 + ch0g * 4);
                    const f32x4 v = acc4[j];
                    uint2 pk;
                    pk.x = cvtpk(fmaxf(v[0] + ofv.x, 0.f), fmaxf(v[1] + ofv.y, 0.f));
                    pk.y = cvtpk(fmaxf(v[2] + ofv.z, 0.f), fmaxf(v[3] + ofv.w, 0.f));
                    *(uint2*)(smem + L_H2C + (nj * 4 + kt2e) * 1024 + lane16 * 16 + sub) = pk;
                }
            }
        }
        __syncthreads();

        // S5: acc5 += h2c @ W4[chunk]
        #pragma unroll
        for (int kt2 = 0; kt2 < 4; kt2++) {
            #pragma unroll
            for (int mi = 0; mi < 5; mi++) {
                const bf16x8 a = *(const bf16x8*)(smem + L_H2C + (mi * 4 + kt2) * 1024 + lane * 16);
                acc5[mi] = __builtin_amdgcn_mfma_f32_16x16x32_bf16(a, b5[kt2], acc5[mi], 0, 0, 0);
            }
        }
        __syncthreads();
    }

    // ---------- P5: 4-col run maxes -> CAT overlay ----------
    #pragma unroll
    for (int mi = 0; mi < 5; mi++) {
        const int run = mi * 4 + lg;
        const int ch = wid * 16 + l15;
        const f32x4 v = acc5[mi];
        const float m4 = fmaxf(fmaxf(v[0], v[1]), fmaxf(v[2], v[3]));
        *(unsigned short*)(smem + L_CAT + run * 512 + ch * 2) = f2bf(m4);
    }
    __syncthreads();

    // ---------- P6: final max + b4 + type_emb ----------
    {
        const int pl = tid >> 8, ch = tid & 255;
        if (bbase + pl < nact) {
            const int gpoly = list[bbase + pl];
            float mx = -3.0e38f;
            #pragma unroll
            for (int j = 0; j < 5; j++)
                mx = fmaxf(mx, bf2f(*(const unsigned short*)(smem + L_CAT +
                        (pl * 5 + j) * 512 + ch * 2)));
            out0[(size_t)gpoly * 256 + ch] = mx + b4[ch] + temb[label[gpoly] * 256 + ch];
        }
    }
}

// ---------------------------------------------------------------------------
// PE: r7 byte-exact proven version. 32 rows/block, all rows, out2-masked.
// ---------------------------------------------------------------------------
#define PR     32
#define P_SINE 0          // 16 frags (kt0..7 x nt0..1)  16384
#define P_PHC  16384      // 32 frags (mt0..1 x kt0..15) 32768

__global__ __launch_bounds__(512, 4) void pe_mfma(
    const float* __restrict__ tgt, const float* __restrict__ out2,
    const float* __restrict__ bp1, const float* __restrict__ bp2,
    const float* __restrict__ pcr, const char* __restrict__ wsb,
    float* __restrict__ out1)
{
    __shared__ __align__(16) char sm[49152];
    const int tid  = threadIdx.x;
    const int wid  = tid >> 6;
    const int lane = tid & 63;
    const int l15  = lane & 15, lg = lane >> 4;
    const int base = blockIdx.x * PR;

    const float lox = pcr[0], loy = pcr[1];
    const float sx = 1.0f / (pcr[3] - pcr[0]), sy = 1.0f / (pcr[4] - pcr[1]);

    // sine B-frags: 1024 slots, 2 per thread
    #pragma unroll
    for (int i = 0; i < 2; i++) {
        const int u = i * 512 + tid;
        const int kt = u >> 7, nt = (u >> 6) & 1, s = u & 63;
        const int row = nt * 16 + (s & 15);
        const int lgs = s >> 4;
        const size_t gp = (size_t)(base + row) * 42;
        const float posx = (tgt[gp + 20] - lox) * sx;
        const float posy = (tgt[gp + 21] - loy) * sy;
        float fv[8];
        #pragma unroll
        for (int e = 0; e < 8; e++) {
            const int ch = kt * 32 + lgs * 8 + e;
            const float pos = (ch < 128) ? posy : posx;
            const int j7 = ch & 127, fi = j7 >> 1;
            const float freq = exp2f(-(float)fi * 0.20762050593046f) * 6.283185307179586f;
            const float arg = pos * freq;
            fv[e] = (j7 & 1) ? __cosf(arg) : __sinf(arg);
        }
        uint4 pk;
        pk.x = cvtpk(fv[0], fv[1]); pk.y = cvtpk(fv[2], fv[3]);
        pk.z = cvtpk(fv[4], fv[5]); pk.w = cvtpk(fv[6], fv[7]);
        *(uint4*)(sm + P_SINE + (kt * 2 + nt) * 1024 + s * 16) = pk;
    }
    __syncthreads();

    const int mw = wid >> 1, nw = wid & 1;

    f32x4 acc5[2][2];
    acc5[0][0] = (f32x4){0.f,0.f,0.f,0.f}; acc5[0][1] = (f32x4){0.f,0.f,0.f,0.f};
    acc5[1][0] = (f32x4){0.f,0.f,0.f,0.f}; acc5[1][1] = (f32x4){0.f,0.f,0.f,0.f};

    #pragma unroll 1
    for (int chunk = 0; chunk < 8; chunk++) {
        const int mt1 = chunk * 4 + mw;
        // prefetch all 8 Wp1 A-frags
        bf16x8 a8[8];
        #pragma unroll
        for (int kk = 0; kk < 8; kk++) {
            const int fid = ((mt1 >> 2) * 2 + (kk >> 2)) * 16 + (mt1 & 3) * 4 + (kk & 3);
            a8[kk] = *(const bf16x8*)(wsb + WS_WP1 + (size_t)fid * 1024 + lane * 16);
        }
        f32x4 acc4 = {0.f, 0.f, 0.f, 0.f};
        #pragma unroll
        for (int kk = 0; kk < 8; kk++) {
            const bf16x8 bb = *(const bf16x8*)(sm + P_SINE + (kk * 2 + nw) * 1024 + lane * 16);
            acc4 = __builtin_amdgcn_mfma_f32_16x16x32_bf16(a8[kk], bb, acc4, 0, 0, 0);
        }
        // issue GEMM2 B-frags (Wp2) for this chunk
        bf16x8 b5[4];
        #pragma unroll
        for (int kj = 0; kj < 2; kj++) {
            #pragma unroll
            for (int njj = 0; njj < 2; njj++) {
                const int ktB = chunk * 2 + kj, ntB = wid * 2 + njj;
                const int fid = (ktB >> 1) * 32 + ((ntB >> 3) & 1) * 16 + (ntB & 7) * 2 + (ktB & 1);
                b5[kj * 2 + njj] = *(const bf16x8*)(wsb + WS_WP2 + (size_t)fid * 1024 + lane * 16);
            }
        }
        // epilogue: + bp1, relu -> PHC A-frags
        {
            const int ch0 = mt1 * 16 + lg * 4;
            const float4 bv = *(const float4*)(bp1 + ch0);
            const int ktA = mt1 >> 1;
            const int slot = l15 + 16 * ((mt1 & 1) * 2 + (lg >> 1));
            uint2 pk;
            pk.x = cvtpk(fmaxf(acc4[0] + bv.x, 0.f), fmaxf(acc4[1] + bv.y, 0.f));
            pk.y = cvtpk(fmaxf(acc4[2] + bv.z, 0.f), fmaxf(acc4[3] + bv.w, 0.f));
            *(uint2*)(sm + P_PHC + (nw * 16 + ktA) * 1024 + slot * 16 + (lg & 1) * 8) = pk;
        }
        __syncthreads();
        // GEMM2: acc5 += phc @ Wp2[chunk]
        #pragma unroll
        for (int kj = 0; kj < 2; kj++) {
            bf16x8 a[2];
            a[0] = *(const bf16x8*)(sm + P_PHC + (0 * 16 + chunk * 2 + kj) * 1024 + lane * 16);
            a[1] = *(const bf16x8*)(sm + P_PHC + (1 * 16 + chunk * 2 + kj) * 1024 + lane * 16);
            #pragma unroll
            for (int njj = 0; njj < 2; njj++) {
                acc5[0][njj] = __builtin_amdgcn_mfma_f32_16x16x32_bf16(a[0], b5[kj * 2 + njj], acc5[0][njj], 0, 0, 0);
                acc5[1][njj] = __builtin_amdgcn_mfma_f32_16x16x32_bf16(a[1], b5[kj * 2 + njj], acc5[1][njj], 0, 0, 0);
            }
        }
        __syncthreads();
    }

    // final: +bp2, masked
    #pragma unroll
    for (int mi = 0; mi < 2; mi++) {
        #pragma unroll
        for (int njj = 0; njj < 2; njj++) {
            const int ch = (wid * 2 + njj) * 16 + l15;
            const float bo = bp2[ch];
            const f32x4 v = acc5[mi][njj];
            #pragma unroll
            for (int r = 0; r < 4; r++) {
                const int row = base + mi * 16 + lg * 4 + r;
                out1[(size_t)row * 256 + ch] = (out2[row] == 0.0f) ? (v[r] + bo) : 0.f;
            }
        }
    }
}

extern "C" void kernel_launch(void* const* d_in, const int* in_sizes, int n_in,
                              void* d_out, int out_size, void* d_ws, size_t ws_size,
                              hipStream_t stream) {
    const float*         tgt   = (const float*)d_in[0];
    const int*           lab   = (const int*)d_in[1];
    const unsigned char* mraw  = (const unsigned char*)d_in[2];
    const float* W1  = (const float*)d_in[3];
    const float* b1  = (const float*)d_in[4];
    const float* g1  = (const float*)d_in[5];
    const float* be1 = (const float*)d_in[6];
    const float* m1  = (const float*)d_in[7];
    const float* v1  = (const float*)d_in[8];
    const float* W2  = (const float*)d_in[9];
    const float* b2  = (const float*)d_in[10];
    const float* W3  = (const float*)d_in[11];
    const float* b3  = (const float*)d_in[12];
    const float* g2  = (const float*)d_in[13];
    const float* be2 = (const float*)d_in[14];
    const float* m2  = (const float*)d_in[15];
    const float* v2  = (const float*)d_in[16];
    const float* W4  = (const float*)d_in[17];
    const float* b4  = (const float*)d_in[18];
    const float* temb = (const float*)d_in[19];
    const float* Wp1 = (const float*)d_in[20];
    const float* bp1 = (const float*)d_in[21];
    const float* Wp2 = (const float*)d_in[22];
    const float* bp2 = (const float*)d_in[23];
    const float* pcr = (const float*)d_in[24];

    float* out0 = (float*)d_out;
    float* out1 = out0 + (size_t)NPOLY * 256;
    float* out2 = out1 + (size_t)NPOLY * 256;

    char*           wsb  = (char*)d_ws;
    int*            cnt  = (int*)(wsb + WS_CNT);
    unsigned short* list = (unsigned short*)(wsb + WS_LIST);
    unsigned short* wsu  = (unsigned short*)d_ws;

    hipFuncSetAttribute(reinterpret_cast<const void*>(enc_mfma),
                        hipFuncAttributeMaxDynamicSharedMemorySize, L_TOT);

    hipMemsetAsync(cnt, 0, 4, stream);
    prep_all<<<1024, 512, 0, stream>>>(W2, W3, W4, Wp1, Wp2, g2, v2, mraw,
                                       wsu, out2, list, cnt, out0);
    enc_mfma<<<NPOLY / NPB, 1024, L_TOT, stream>>>(
        tgt, lab, list, cnt, W1, b1, g1, be1, m1, v1, b2, b3, g2, be2, m2, v2,
        b4, temb, wsb, out0);
    pe_mfma<<<NPOLY / PR, 512, 0, stream>>>(tgt, out2, bp1, bp2, pcr, wsb, out1);
}

// Round 13
// 115.202 us; speedup vs baseline: 1.2863x; 1.2863x over previous
//
#include <hip/hip_runtime.h>

// ---------------------------------------------------------------------------
// MapEncoder, round 13: EXACT round-7-proven two-kernel configuration
// (enc 90us + pe 15us, 120.2us total, absmax 1.95e-3), plus s_setprio(1/0)
// around MFMA clusters (T5 — scheduler hint only, zero correctness risk).
// Fusion/compaction-of-PE abandoned: two unexplained out1 failures (r9, r12).
// Fragment convention (HW-verified m89/m91): lane&15 = M/N index, 8 contiguous
// k per lane at k-group (lane>>4)*8; D: col=lane&15, row=4*(lane>>4)+reg.
// ---------------------------------------------------------------------------

#define NPOLY 16384
#define NPB   4
#define NC    80
#define NT    5

typedef float f32x4  __attribute__((ext_vector_type(4)));
typedef short bf16x8 __attribute__((ext_vector_type(8)));

__device__ __forceinline__ unsigned short f2bf(float x) {
    union { float f; unsigned u; } v; v.f = x;
    unsigned r = v.u + 0x7FFF + ((v.u >> 16) & 1);
    return (unsigned short)(r >> 16);
}
__device__ __forceinline__ float bf2f(unsigned short s) {
    union { unsigned u; float f; } v; v.u = ((unsigned)s) << 16;
    return v.f;
}
// single-instruction packed f32x2 -> bf16x2 (RNE), lo=a hi=b
__device__ __forceinline__ unsigned cvtpk(float a, float b) {
    unsigned r;
    asm("v_cvt_pk_bf16_f32 %0, %1, %2" : "=v"(r) : "v"(a), "v"(b));
    return r;
}
__device__ __forceinline__ float bflo(unsigned u) {
    union { unsigned x; float f; } w; w.x = u << 16; return w.f;
}
__device__ __forceinline__ float bfhi(unsigned u) {
    union { unsigned x; float f; } w; w.x = u & 0xFFFF0000u; return w.f;
}

// ---- workspace layout (bytes) ----
#define WS_CNT  0
#define WS_LIST 64         // u16 list[16384]
#define WS_W2   33792      // 64 frags  (A-style, M=256 K=128)
#define WS_W3   99328      // 256 frags (A-style, M=256 K=512)
#define WS_W4   361472     // 128 frags (B-style, N=256 K=256)
#define WS_WP1  492544     // 256 frags (A-style, M=512 K=256)
#define WS_WP2  754688     // 256 frags (B-style, N=256 K=512)

// ---- enc LDS layout (dynamic, bytes) ----
#define L_CAT   0          // 40 frags: h B-operand (kt0..7, nt0..4)    40960
                           //   overlays: feat f32[80] stride 36B (P0/P1)
                           //             runs bf16[20][256] (P5/P6)
#define L_H1    40960      // 20 frags h1 B-op; later h2c A-frags       20480
#define L_H2C   40960
#define L_PFRAG 61440      // 8 frags: pooled B-operand                  8192
#define L_SC    69632      // sc2 f32[256]                               1024
#define L_OF    70656      // (b3-m2)*sc+be2 f32[256]                    1024
#define L_APOF  71680      // apof f32[4][256]                           4096
#define L_TOT   75776

// ---------------------------------------------------------------------------
__global__ __launch_bounds__(256) void norm_mask(
    const unsigned char* __restrict__ mraw, float* __restrict__ out2,
    unsigned short* __restrict__ list, int* __restrict__ cnt,
    float* __restrict__ out0)
{
    __shared__ int s_nz;
    __shared__ unsigned char s_v[256];
    const int tid = threadIdx.x;
    if (tid == 0) s_nz = 0;
    __syncthreads();
    int local = 0;
    for (int j = 0; j < 64; j++) {
        const int i = tid * 64 + j;
        if ((i & 3) != 0) local |= mraw[i];
    }
    if (local) atomicOr(&s_nz, 1);
    __syncthreads();
    const bool isByte = (s_nz != 0);
    const int i = blockIdx.x * 256 + tid;
    const unsigned char v = isByte ? (mraw[i] != 0) : (((const int*)mraw)[i] != 0);
    out2[i] = v ? 0.0f : 1.0f;
    s_v[tid] = v;
    if (v) { const int pos = atomicAdd(cnt, 1); list[pos] = (unsigned short)i; }
    __syncthreads();
    const float4 z = {0.f, 0.f, 0.f, 0.f};
    for (int r8 = 0; r8 < 32; r8++) {
        const int row = r8 * 8 + (tid >> 5);
        if (!s_v[row]) {
            float4* dst = (float4*)(out0 + (size_t)(blockIdx.x * 256 + row) * 256);
            dst[tid & 31] = z;
            dst[(tid & 31) + 32] = z;
        }
    }
}

// ---------------------------------------------------------------------------
__global__ __launch_bounds__(512) void prep_weights(
    const float* __restrict__ W2, const float* __restrict__ W3,
    const float* __restrict__ W4, const float* __restrict__ Wp1,
    const float* __restrict__ Wp2, unsigned short* __restrict__ wsu)
{
    const int bid = blockIdx.x;
    const float* src; int mode, KS, ld, fid; size_t dst;
    if      (bid < 64)  { src = W2;  mode = 0; KS = 0; ld = 256; fid = bid;       dst = WS_W2;  }
    else if (bid < 320) { src = W3;  mode = 1; KS = 4; ld = 256; fid = bid - 64;  dst = WS_W3;  }
    else if (bid < 448) { src = W4;  mode = 2; KS = 0; ld = 256; fid = bid - 320; dst = WS_W4;  }
    else if (bid < 704) { src = Wp1; mode = 1; KS = 2; ld = 512; fid = bid - 448; dst = WS_WP1; }
    else                { src = Wp2; mode = 2; KS = 0; ld = 256; fid = bid - 704; dst = WS_WP2; }

    int mt, kt;
    if (mode == 0) { mt = fid & 15; kt = fid >> 4; }
    else if (mode == 1) {
        const int low = fid & 15, hi = fid >> 4;
        mt = (hi / KS) * 4 + (low >> 2);
        kt = (hi % KS) * 4 + (low & 3);
    } else {
        const int low = fid & 31;
        kt = (fid >> 5) * 2 + (low & 1);
        mt = ((low >> 4) & 1) * 8 + ((low >> 1) & 7);
    }
    const int t   = threadIdx.x;
    const int l15 = t & 15, e = (t >> 4) & 7, lg = (t >> 7) & 3;
    const int m = mt * 16 + l15;
    const int k = kt * 32 + lg * 8 + e;
    wsu[dst / 2 + (size_t)fid * 512 + (l15 + 16 * lg) * 8 + e] = f2bf(src[(size_t)k * ld + m]);
}

// ---------------------------------------------------------------------------
// main encoder (active polylines only). 512 threads = 8 waves.
// ---------------------------------------------------------------------------
__global__ __launch_bounds__(512, 4) void enc_mfma(
    const float* __restrict__ tgt, const int* __restrict__ label,
    const unsigned short* __restrict__ list, const int* __restrict__ cnt,
    const float* __restrict__ W1, const float* __restrict__ b1,
    const float* __restrict__ g1, const float* __restrict__ be1,
    const float* __restrict__ m1, const float* __restrict__ v1,
    const float* __restrict__ b2, const float* __restrict__ b3,
    const float* __restrict__ g2, const float* __restrict__ be2,
    const float* __restrict__ m2, const float* __restrict__ v2,
    const float* __restrict__ b4, const float* __restrict__ temb,
    const char* __restrict__ wsb, float* __restrict__ out0)
{
    extern __shared__ char smem[];
    const int nact  = cnt[0];
    const int bbase = blockIdx.x * NPB;
    if (bbase >= nact) return;

    const int tid  = threadIdx.x;
    const int wid  = tid >> 6;
    const int lane = tid & 63;
    const int l15  = lane & 15, lg = lane >> 4;

    // ---------- P0: feat (padded 36B rows, CAT overlay) + bn2 folded ------
    if (tid < NC) {
        const int c = tid, pl = c / 20, p = c - pl * 20;
        const int gpoly = list[min(bbase + pl, nact - 1)];
        const size_t gp = (size_t)gpoly * 42;
        const float px = tgt[gp + p * 2],     py = tgt[gp + p * 2 + 1];
        const float qx = tgt[gp + p * 2 + 2], qy = tgt[gp + p * 2 + 3];
        const float cx = tgt[gp + 20],        cy = tgt[gp + 21];
        const float vx = qx - px, vy = qy - py;
        const float inv = 1.0f / (sqrtf(vx * vx + vy * vy) + 1.0f + 1e-6f);
        float* f = (float*)(smem + L_CAT + c * 36);
        f[0] = px - cx; f[1] = py - cy; f[2] = vx; f[3] = vy;
        f[4] = vx * inv; f[5] = vy * inv;
    }
    if (tid < 256) {
        const float sc = rsqrtf(v2[tid] + 1e-5f) * g2[tid];
        ((float*)(smem + L_SC))[tid] = sc;
        ((float*)(smem + L_OF))[tid] = (b3[tid] - m2[tid]) * sc + be2[tid];
    }
    __syncthreads();

    // ---------- P1: h1 = relu(bn1(feat@W1+b1)) -> B-frags ----------
    {
        const int ch = tid & 127, cblk = tid >> 7;
        float w[6];
        #pragma unroll
        for (int j = 0; j < 6; j++) w[j] = W1[j * 128 + ch];
        const float sc1  = rsqrtf(v1[ch] + 1e-5f) * g1[ch];
        const float off1 = (b1[ch] - m1[ch]) * sc1 + be1[ch];
        const int kt = ch >> 5, koff = ch & 31;
        const int lane16 = 16 * (koff >> 3);
        #pragma unroll 4
        for (int i = 0; i < 20; i++) {
            const int c = i * 4 + cblk;
            const float* f = (const float*)(smem + L_CAT + c * 36);
            float a = 0.f;
            #pragma unroll
            for (int j = 0; j < 6; j++) a = fmaf(f[j], w[j], a);
            a = fmaxf(fmaf(a, sc1, off1), 0.0f);
            *(unsigned short*)(smem + L_H1 + (kt * NT + (c >> 4)) * 1024 +
                               ((c & 15) + lane16) * 16 + (koff & 7) * 2) = f2bf(a);
        }
    }
    __syncthreads();

    // ---------- S3: h^T = W2^T @ h1^T (M=256,N=80,K=128) ----------
    {
        bf16x8 a8[8];                      // all 8 A-frags up front
        #pragma unroll
        for (int kt = 0; kt < 4; kt++) {
            #pragma unroll
            for (int mi = 0; mi < 2; mi++)
                a8[kt * 2 + mi] = *(const bf16x8*)(wsb + WS_W2 +
                    (size_t)(kt * 16 + wid * 2 + mi) * 1024 + lane * 16);
        }
        f32x4 acc[2][5];
        #pragma unroll
        for (int a = 0; a < 2; a++)
            #pragma unroll
            for (int b = 0; b < 5; b++) acc[a][b] = (f32x4){0.f, 0.f, 0.f, 0.f};

        __builtin_amdgcn_s_setprio(1);
        #pragma unroll
        for (int kt = 0; kt < 4; kt++) {
            #pragma unroll
            for (int nj = 0; nj < 5; nj++) {
                const bf16x8 bb = *(const bf16x8*)(smem + L_H1 + (kt * NT + nj) * 1024 + lane * 16);
                acc[0][nj] = __builtin_amdgcn_mfma_f32_16x16x32_bf16(a8[kt * 2 + 0], bb, acc[0][nj], 0, 0, 0);
                acc[1][nj] = __builtin_amdgcn_mfma_f32_16x16x32_bf16(a8[kt * 2 + 1], bb, acc[1][nj], 0, 0, 0);
            }
        }
        __builtin_amdgcn_s_setprio(0);
        // epilogue: + b2 -> CAT B-frags
        #pragma unroll
        for (int mi = 0; mi < 2; mi++) {
            const int mt = wid * 2 + mi, chb = mt * 16 + lg * 4;
            const float4 bv = *(const float4*)(b2 + chb);
            const int kt = chb >> 5, koff = chb & 31;
            const int lane16 = l15 + 16 * (koff >> 3);
            #pragma unroll
            for (int nj = 0; nj < 5; nj++) {
                const f32x4 v = acc[mi][nj];
                uint2 pk;
                pk.x = cvtpk(v[0] + bv.x, v[1] + bv.y);
                pk.y = cvtpk(v[2] + bv.z, v[3] + bv.w);
                *(uint2*)(smem + L_CAT + (kt * NT + nj) * 1024 + lane16 * 16 + (koff & 7) * 2) = pk;
            }
        }
    }
    __syncthreads();

    // pooled-GEMM A-frags (W3 kt 8..15): issue loads NOW, hide under P3
    bf16x8 ap8[16];
    #pragma unroll
    for (int mi = 0; mi < 2; mi++) {
        const int mt = wid * 2 + mi;
        #pragma unroll
        for (int kk = 0; kk < 8; kk++) {
            const int kt = 8 + kk;
            const int fid = ((mt >> 2) * 4 + (kt >> 2)) * 16 + (mt & 3) * 4 + (kt & 3);
            ap8[mi * 8 + kk] = *(const bf16x8*)(wsb + WS_W3 + (size_t)fid * 1024 + lane * 16);
        }
    }

    // ---------- P3: pooled = max_p h, written directly as B-frags --------
    if (tid < 128) {
        const int pl = tid >> 5, grp = tid & 31;
        const int fragbase = (grp >> 2) * NT;
        const int off16 = 16 * (grp & 3);
        float mx[8];
        #pragma unroll
        for (int e = 0; e < 8; e++) mx[e] = -3.0e38f;
        #pragma unroll 4
        for (int p = 0; p < 20; p++) {
            int pp = p + grp;                 // rotate start to spread banks
            pp -= (pp >= 40) ? 40 : ((pp >= 20) ? 20 : 0);
            const int c = pl * 20 + pp;
            const uint4 v = *(const uint4*)(smem + L_CAT +
                (fragbase + (c >> 4)) * 1024 + ((c & 15) + off16) * 16);
            mx[0] = fmaxf(mx[0], bflo(v.x)); mx[1] = fmaxf(mx[1], bfhi(v.x));
            mx[2] = fmaxf(mx[2], bflo(v.y)); mx[3] = fmaxf(mx[3], bfhi(v.y));
            mx[4] = fmaxf(mx[4], bflo(v.z)); mx[5] = fmaxf(mx[5], bfhi(v.z));
            mx[6] = fmaxf(mx[6], bflo(v.w)); mx[7] = fmaxf(mx[7], bfhi(v.w));
        }
        uint4 pk;
        pk.x = cvtpk(mx[0], mx[1]); pk.y = cvtpk(mx[2], mx[3]);
        pk.z = cvtpk(mx[4], mx[5]); pk.w = cvtpk(mx[6], mx[7]);
        // B-frag: frag kt=grp>>2, slot = pl + 16*(grp&3)
        *(uint4*)(smem + L_PFRAG + (grp >> 2) * 1024 + (pl + 16 * (grp & 3)) * 16) = pk;
    }
    __syncthreads();

    // ---------- pooled GEMM: ap = pooled @ W3[256:]; APOF = ap*sc + OF ----
    {
        f32x4 accp0 = {0.f, 0.f, 0.f, 0.f}, accp1 = {0.f, 0.f, 0.f, 0.f};
        __builtin_amdgcn_s_setprio(1);
        #pragma unroll
        for (int kk = 0; kk < 8; kk++) {
            const bf16x8 bb = *(const bf16x8*)(smem + L_PFRAG + kk * 1024 + lane * 16);
            accp0 = __builtin_amdgcn_mfma_f32_16x16x32_bf16(ap8[kk],     bb, accp0, 0, 0, 0);
            accp1 = __builtin_amdgcn_mfma_f32_16x16x32_bf16(ap8[8 + kk], bb, accp1, 0, 0, 0);
        }
        __builtin_amdgcn_s_setprio(0);
        if (l15 < 4) {
            #pragma unroll
            for (int mi = 0; mi < 2; mi++) {
                const f32x4 v = mi ? accp1 : accp0;
                const int ch0 = (wid * 2 + mi) * 16 + lg * 4;
                const float4 scv = *(const float4*)(smem + L_SC + ch0 * 4);
                const float4 ofv = *(const float4*)(smem + L_OF + ch0 * 4);
                float4 o;
                o.x = fmaf(v[0], scv.x, ofv.x); o.y = fmaf(v[1], scv.y, ofv.y);
                o.z = fmaf(v[2], scv.z, ofv.z); o.w = fmaf(v[3], scv.w, ofv.w);
                *(float4*)(smem + L_APOF + l15 * 1024 + ch0 * 4) = o;
            }
        }
    }
    __syncthreads();

    // APOF per-nj lane bases (poly = col/20)
    unsigned abase[5];
    #pragma unroll
    for (int nj = 0; nj < 5; nj++)
        abase[5 > nj ? nj : 0] = L_APOF + (unsigned)((nj * 16 + l15) / 20) * 1024;

    // ---------- P4: 2 chunks of 128 out-ch: S4 (K=256) fused w/ S5 --------
    f32x4 acc5[5][2];
    #pragma unroll
    for (int a = 0; a < 5; a++) {
        acc5[a][0] = (f32x4){0.f, 0.f, 0.f, 0.f};
        acc5[a][1] = (f32x4){0.f, 0.f, 0.f, 0.f};
    }

    #pragma unroll 1
    for (int chunk = 0; chunk < 2; chunk++) {
        const int mtg = chunk * 8 + wid;
        // prefetch all 8 W3 A-frags (kt 0..7) for this chunk
        bf16x8 a4[8];
        #pragma unroll
        for (int kk = 0; kk < 8; kk++) {
            const int fid = ((mtg >> 2) * 4 + (kk >> 2)) * 16 + (mtg & 3) * 4 + (kk & 3);
            a4[kk] = *(const bf16x8*)(wsb + WS_W3 + (size_t)fid * 1024 + lane * 16);
        }
        f32x4 acc4[5];
        #pragma unroll
        for (int s = 0; s < 5; s++) acc4[s] = (f32x4){0.f, 0.f, 0.f, 0.f};

        __builtin_amdgcn_s_setprio(1);
        #pragma unroll
        for (int ktg = 0; ktg < 8; ktg++) {
            #pragma unroll
            for (int nj = 0; nj < 5; nj++) {
                const bf16x8 bb = *(const bf16x8*)(smem + L_CAT + (ktg * NT + nj) * 1024 + lane * 16);
                acc4[nj] = __builtin_amdgcn_mfma_f32_16x16x32_bf16(a4[ktg], bb, acc4[nj], 0, 0, 0);
            }
        }
        __builtin_amdgcn_s_setprio(0);
        // issue S5 B-frags (W4) now; latency hides under epilogue+barrier
        bf16x8 b5[8];
        #pragma unroll
        for (int kt2 = 0; kt2 < 4; kt2++) {
            #pragma unroll
            for (int njb = 0; njb < 2; njb++) {
                const int ktB = chunk * 4 + kt2, ntB = wid * 2 + njb;
                const int fid = (ktB >> 1) * 32 + ((ntB >> 3) & 1) * 16 + (ntB & 7) * 2 + (ktB & 1);
                b5[kt2 * 2 + njb] = *(const bf16x8*)(wsb + WS_W4 + (size_t)fid * 1024 + lane * 16);
            }
        }
        // epilogue: h2 = relu(acc*sc + APOF) -> h2c A-frags
        {
            const int choff = wid * 16 + lg * 4;
            const int ch0 = mtg * 16 + lg * 4;
            const float4 scv = *(const float4*)(smem + L_SC + ch0 * 4);
            const int kt2 = choff >> 5;
            const int lane16 = l15 + 16 * ((choff & 31) >> 3);
            const int sub = (lg & 1) * 8;
            #pragma unroll
            for (int nj = 0; nj < 5; nj++) {
                const float4 ofv = *(const float4*)(smem + abase[nj] + ch0 * 4);
                const f32x4 v = acc4[nj];
                uint2 pk;
                pk.x = cvtpk(fmaxf(fmaf(v[0], scv.x, ofv.x), 0.f),
                             fmaxf(fmaf(v[1], scv.y, ofv.y), 0.f));
                pk.y = cvtpk(fmaxf(fmaf(v[2], scv.z, ofv.z), 0.f),
                             fmaxf(fmaf(v[3], scv.w, ofv.w), 0.f));
                *(uint2*)(smem + L_H2C + (nj * 4 + kt2) * 1024 + lane16 * 16 + sub) = pk;
            }
        }
        __syncthreads();

        // S5: acc5 += h2c @ W4[chunk]
        __builtin_amdgcn_s_setprio(1);
        #pragma unroll
        for (int kt2 = 0; kt2 < 4; kt2++) {
            #pragma unroll
            for (int mi = 0; mi < 5; mi++) {
                const bf16x8 a = *(const bf16x8*)(smem + L_H2C + (mi * 4 + kt2) * 1024 + lane * 16);
                acc5[mi][0] = __builtin_amdgcn_mfma_f32_16x16x32_bf16(a, b5[kt2 * 2 + 0], acc5[mi][0], 0, 0, 0);
                acc5[mi][1] = __builtin_amdgcn_mfma_f32_16x16x32_bf16(a, b5[kt2 * 2 + 1], acc5[mi][1], 0, 0, 0);
            }
        }
        __builtin_amdgcn_s_setprio(0);
        __syncthreads();
    }

    // ---------- P5: 4-col run maxes -> CAT overlay ----------
    #pragma unroll
    for (int mi = 0; mi < 5; mi++) {
        const int run = mi * 4 + lg;
        #pragma unroll
        for (int njb = 0; njb < 2; njb++) {
            const int ch = (wid * 2 + njb) * 16 + l15;
            const f32x4 v = acc5[mi][njb];
            const float m4 = fmaxf(fmaxf(v[0], v[1]), fmaxf(v[2], v[3]));
            *(unsigned short*)(smem + L_CAT + run * 512 + ch * 2) = f2bf(m4);
        }
    }
    __syncthreads();

    // ---------- P6: final max + b4 + type_emb ----------
    #pragma unroll
    for (int i = 0; i < 2; i++) {
        const int idx = i * 512 + tid, pl = idx >> 8, ch = idx & 255;
        if (bbase + pl < nact) {
            const int gpoly = list[bbase + pl];
            float mx = -3.0e38f;
            #pragma unroll
            for (int j = 0; j < 5; j++)
                mx = fmaxf(mx, bf2f(*(const unsigned short*)(smem + L_CAT +
                        (pl * 5 + j) * 512 + ch * 2)));
            out0[(size_t)gpoly * 256 + ch] = mx + b4[ch] + temb[label[gpoly] * 256 + ch];
        }
    }
}

// ---------------------------------------------------------------------------
// PE: r7 byte-exact proven version. 32 rows/block x 512 blocks, out2-masked.
// ---------------------------------------------------------------------------
#define PR     32
#define P_SINE 0          // 16 frags (kt0..7 x nt0..1)  16384
#define P_PHC  16384      // 32 frags (mt0..1 x kt0..15) 32768

__global__ __launch_bounds__(512, 4) void pe_mfma(
    const float* __restrict__ tgt, const float* __restrict__ out2,
    const float* __restrict__ bp1, const float* __restrict__ bp2,
    const float* __restrict__ pcr, const char* __restrict__ wsb,
    float* __restrict__ out1)
{
    __shared__ __align__(16) char sm[49152];
    const int tid  = threadIdx.x;
    const int wid  = tid >> 6;
    const int lane = tid & 63;
    const int l15  = lane & 15, lg = lane >> 4;
    const int base = blockIdx.x * PR;

    const float lox = pcr[0], loy = pcr[1];
    const float sx = 1.0f / (pcr[3] - pcr[0]), sy = 1.0f / (pcr[4] - pcr[1]);

    // sine B-frags: 1024 slots, 2 per thread
    #pragma unroll
    for (int i = 0; i < 2; i++) {
        const int u = i * 512 + tid;
        const int kt = u >> 7, nt = (u >> 6) & 1, s = u & 63;
        const int row = nt * 16 + (s & 15);
        const int lgs = s >> 4;
        const size_t gp = (size_t)(base + row) * 42;
        const float posx = (tgt[gp + 20] - lox) * sx;
        const float posy = (tgt[gp + 21] - loy) * sy;
        float fv[8];
        #pragma unroll
        for (int e = 0; e < 8; e++) {
            const int ch = kt * 32 + lgs * 8 + e;
            const float pos = (ch < 128) ? posy : posx;
            const int j7 = ch & 127, fi = j7 >> 1;
            const float freq = exp2f(-(float)fi * 0.20762050593046f) * 6.283185307179586f;
            const float arg = pos * freq;
            fv[e] = (j7 & 1) ? __cosf(arg) : __sinf(arg);
        }
        uint4 pk;
        pk.x = cvtpk(fv[0], fv[1]); pk.y = cvtpk(fv[2], fv[3]);
        pk.z = cvtpk(fv[4], fv[5]); pk.w = cvtpk(fv[6], fv[7]);
        *(uint4*)(sm + P_SINE + (kt * 2 + nt) * 1024 + s * 16) = pk;
    }
    __syncthreads();

    const int mw = wid >> 1, nw = wid & 1;

    f32x4 acc5[2][2];
    acc5[0][0] = (f32x4){0.f,0.f,0.f,0.f}; acc5[0][1] = (f32x4){0.f,0.f,0.f,0.f};
    acc5[1][0] = (f32x4){0.f,0.f,0.f,0.f}; acc5[1][1] = (f32x4){0.f,0.f,0.f,0.f};

    #pragma unroll 1
    for (int chunk = 0; chunk < 8; chunk++) {
        const int mt1 = chunk * 4 + mw;
        // prefetch all 8 Wp1 A-frags
        bf16x8 a8[8];
        #pragma unroll
        for (int kk = 0; kk < 8; kk++) {
            const int fid = ((mt1 >> 2) * 2 + (kk >> 2)) * 16 + (mt1 & 3) * 4 + (kk & 3);
            a8[kk] = *(const bf16x8*)(wsb + WS_WP1 + (size_t)fid * 1024 + lane * 16);
        }
        f32x4 acc4 = {0.f, 0.f, 0.f, 0.f};
        __builtin_amdgcn_s_setprio(1);
        #pragma unroll
        for (int kk = 0; kk < 8; kk++) {
            const bf16x8 bb = *(const bf16x8*)(sm + P_SINE + (kk * 2 + nw) * 1024 + lane * 16);
            acc4 = __builtin_amdgcn_mfma_f32_16x16x32_bf16(a8[kk], bb, acc4, 0, 0, 0);
        }
        __builtin_amdgcn_s_setprio(0);
        // issue GEMM2 B-frags (Wp2) for this chunk
        bf16x8 b5[4];
        #pragma unroll
        for (int kj = 0; kj < 2; kj++) {
            #pragma unroll
            for (int njj = 0; njj < 2; njj++) {
                const int ktB = chunk * 2 + kj, ntB = wid * 2 + njj;
                const int fid = (ktB >> 1) * 32 + ((ntB >> 3) & 1) * 16 + (ntB & 7) * 2 + (ktB & 1);
                b5[kj * 2 + njj] = *(const bf16x8*)(wsb + WS_WP2 + (size_t)fid * 1024 + lane * 16);
            }
        }
        // epilogue: + bp1, relu -> PHC A-frags
        {
            const int ch0 = mt1 * 16 + lg * 4;
            const float4 bv = *(const float4*)(bp1 + ch0);
            const int ktA = mt1 >> 1;
            const int slot = l15 + 16 * ((mt1 & 1) * 2 + (lg >> 1));
            uint2 pk;
            pk.x = cvtpk(fmaxf(acc4[0] + bv.x, 0.f), fmaxf(acc4[1] + bv.y, 0.f));
            pk.y = cvtpk(fmaxf(acc4[2] + bv.z, 0.f), fmaxf(acc4[3] + bv.w, 0.f));
            *(uint2*)(sm + P_PHC + (nw * 16 + ktA) * 1024 + slot * 16 + (lg & 1) * 8) = pk;
        }
        __syncthreads();
        // GEMM2: acc5 += phc @ Wp2[chunk]
        __builtin_amdgcn_s_setprio(1);
        #pragma unroll
        for (int kj = 0; kj < 2; kj++) {
            bf16x8 a[2];
            a[0] = *(const bf16x8*)(sm + P_PHC + (0 * 16 + chunk * 2 + kj) * 1024 + lane * 16);
            a[1] = *(const bf16x8*)(sm + P_PHC + (1 * 16 + chunk * 2 + kj) * 1024 + lane * 16);
            #pragma unroll
            for (int njj = 0; njj < 2; njj++) {
                acc5[0][njj] = __builtin_amdgcn_mfma_f32_16x16x32_bf16(a[0], b5[kj * 2 + njj], acc5[0][njj], 0, 0, 0);
                acc5[1][njj] = __builtin_amdgcn_mfma_f32_16x16x32_bf16(a[1], b5[kj * 2 + njj], acc5[1][njj], 0, 0, 0);
            }
        }
        __builtin_amdgcn_s_setprio(0);
        __syncthreads();
    }

    // final: +bp2, masked
    #pragma unroll
    for (int mi = 0; mi < 2; mi++) {
        #pragma unroll
        for (int njj = 0; njj < 2; njj++) {
            const int ch = (wid * 2 + njj) * 16 + l15;
            const float bo = bp2[ch];
            const f32x4 v = acc5[mi][njj];
            #pragma unroll
            for (int r = 0; r < 4; r++) {
                const int row = base + mi * 16 + lg * 4 + r;
                out1[(size_t)row * 256 + ch] = (out2[row] == 0.0f) ? (v[r] + bo) : 0.f;
            }
        }
    }
}

extern "C" void kernel_launch(void* const* d_in, const int* in_sizes, int n_in,
                              void* d_out, int out_size, void* d_ws, size_t ws_size,
                              hipStream_t stream) {
    const float*         tgt   = (const float*)d_in[0];
    const int*           lab   = (const int*)d_in[1];
    const unsigned char* mraw  = (const unsigned char*)d_in[2];
    const float* W1  = (const float*)d_in[3];
    const float* b1  = (const float*)d_in[4];
    const float* g1  = (const float*)d_in[5];
    const float* be1 = (const float*)d_in[6];
    const float* m1  = (const float*)d_in[7];
    const float* v1  = (const float*)d_in[8];
    const float* W2  = (const float*)d_in[9];
    const float* b2  = (const float*)d_in[10];
    const float* W3  = (const float*)d_in[11];
    const float* b3  = (const float*)d_in[12];
    const float* g2  = (const float*)d_in[13];
    const float* be2 = (const float*)d_in[14];
    const float* m2  = (const float*)d_in[15];
    const float* v2  = (const float*)d_in[16];
    const float* W4  = (const float*)d_in[17];
    const float* b4  = (const float*)d_in[18];
    const float* temb = (const float*)d_in[19];
    const float* Wp1 = (const float*)d_in[20];
    const float* bp1 = (const float*)d_in[21];
    const float* Wp2 = (const float*)d_in[22];
    const float* bp2 = (const float*)d_in[23];
    const float* pcr = (const float*)d_in[24];

    float* out0 = (float*)d_out;
    float* out1 = out0 + (size_t)NPOLY * 256;
    float* out2 = out1 + (size_t)NPOLY * 256;

    char*           wsb  = (char*)d_ws;
    int*            cnt  = (int*)(wsb + WS_CNT);
    unsigned short* list = (unsigned short*)(wsb + WS_LIST);
    unsigned short* wsu  = (unsigned short*)d_ws;

    hipFuncSetAttribute(reinterpret_cast<const void*>(enc_mfma),
                        hipFuncAttributeMaxDynamicSharedMemorySize, L_TOT);

    hipMemsetAsync(cnt, 0, 4, stream);
    norm_mask<<<NPOLY / 256, 256, 0, stream>>>(mraw, out2, list, cnt, out0);
    prep_weights<<<960, 512, 0, stream>>>(W2, W3, W4, Wp1, Wp2, wsu);
    enc_mfma<<<NPOLY / NPB, 512, L_TOT, stream>>>(
        tgt, lab, list, cnt, W1, b1, g1, be1, m1, v1, b2, b3, g2, be2, m2, v2,
        b4, temb, wsb, out0);
    pe_mfma<<<NPOLY / PR, 512, 0, stream>>>(tgt, out2, bp1, bp2, pcr, wsb, out1);
}

// Round 15
// 112.742 us; speedup vs baseline: 1.3144x; 1.0218x over previous
//
#include <hip/hip_runtime.h>

// ---------------------------------------------------------------------------
// MapEncoder, round 15: round-13-proven enc+pe kernels verbatim (115.2us,
// absmax 1.95e-3), with norm_mask folded into prep_weights (prep_all, the
// r8/r9-validated pattern) to drop one launch. PE is FROZEN at the r7/r13
// body: three independent PE restructures (r9 compaction, r12 fusion,
// r14 PR=64) all failed output 1 at ~7.5e-2 with no localizable defect.
// Fragment convention (HW-verified m89/m91): lane&15 = M/N index, 8
// contiguous k per lane at k-group (lane>>4)*8; D: col=lane&15,
// row=4*(lane>>4)+reg.
// ---------------------------------------------------------------------------

#define NPOLY 16384
#define NPB   4
#define NC    80
#define NT    5

typedef float f32x4  __attribute__((ext_vector_type(4)));
typedef short bf16x8 __attribute__((ext_vector_type(8)));

__device__ __forceinline__ unsigned short f2bf(float x) {
    union { float f; unsigned u; } v; v.f = x;
    unsigned r = v.u + 0x7FFF + ((v.u >> 16) & 1);
    return (unsigned short)(r >> 16);
}
__device__ __forceinline__ float bf2f(unsigned short s) {
    union { unsigned u; float f; } v; v.u = ((unsigned)s) << 16;
    return v.f;
}
// single-instruction packed f32x2 -> bf16x2 (RNE), lo=a hi=b
__device__ __forceinline__ unsigned cvtpk(float a, float b) {
    unsigned r;
    asm("v_cvt_pk_bf16_f32 %0, %1, %2" : "=v"(r) : "v"(a), "v"(b));
    return r;
}
__device__ __forceinline__ float bflo(unsigned u) {
    union { unsigned x; float f; } w; w.x = u << 16; return w.f;
}
__device__ __forceinline__ float bfhi(unsigned u) {
    union { unsigned x; float f; } w; w.x = u & 0xFFFF0000u; return w.f;
}

// ---- workspace layout (bytes) ----
#define WS_CNT  0
#define WS_LIST 64         // u16 list[16384]
#define WS_W2   33792      // 64 frags  (A-style, M=256 K=128)
#define WS_W3   99328      // 256 frags (A-style, M=256 K=512)
#define WS_W4   361472     // 128 frags (B-style, N=256 K=256)
#define WS_WP1  492544     // 256 frags (A-style, M=512 K=256)
#define WS_WP2  754688     // 256 frags (B-style, N=256 K=512)

// ---- enc LDS layout (dynamic, bytes) ----
#define L_CAT   0          // 40 frags: h B-operand (kt0..7, nt0..4)    40960
#define L_H1    40960      // 20 frags h1 B-op; later h2c A-frags       20480
#define L_H2C   40960
#define L_PFRAG 61440      // 8 frags: pooled B-operand                  8192
#define L_SC    69632      // sc2 f32[256]                               1024
#define L_OF    70656      // (b3-m2)*sc+be2 f32[256]                    1024
#define L_APOF  71680      // apof f32[4][256]                           4096
#define L_TOT   75776

// ---------------------------------------------------------------------------
// prep_all: bid<960 -> weight frag prep; bid>=960 -> mask norm/compaction +
// out2 + zero inactive out0 rows. (r8/r9-validated pattern.)
// ---------------------------------------------------------------------------
__global__ __launch_bounds__(512) void prep_all(
    const float* __restrict__ W2, const float* __restrict__ W3,
    const float* __restrict__ W4, const float* __restrict__ Wp1,
    const float* __restrict__ Wp2, const unsigned char* __restrict__ mraw,
    unsigned short* __restrict__ wsu, float* __restrict__ out2,
    unsigned short* __restrict__ list, int* __restrict__ cnt,
    float* __restrict__ out0)
{
    const int bid = blockIdx.x;
    const int tid = threadIdx.x;
    if (bid < 960) {
        const float* src; int mode, KS, ld, fid; size_t dst;
        if      (bid < 64)  { src = W2;  mode = 0; KS = 0; ld = 256; fid = bid;       dst = WS_W2;  }
        else if (bid < 320) { src = W3;  mode = 1; KS = 4; ld = 256; fid = bid - 64;  dst = WS_W3;  }
        else if (bid < 448) { src = W4;  mode = 2; KS = 0; ld = 256; fid = bid - 320; dst = WS_W4;  }
        else if (bid < 704) { src = Wp1; mode = 1; KS = 2; ld = 512; fid = bid - 448; dst = WS_WP1; }
        else                { src = Wp2; mode = 2; KS = 0; ld = 256; fid = bid - 704; dst = WS_WP2; }

        int mt, kt;
        if (mode == 0) { mt = fid & 15; kt = fid >> 4; }
        else if (mode == 1) {
            const int low = fid & 15, hi = fid >> 4;
            mt = (hi / KS) * 4 + (low >> 2);
            kt = (hi % KS) * 4 + (low & 3);
        } else {
            const int low = fid & 31;
            kt = (fid >> 5) * 2 + (low & 1);
            mt = ((low >> 4) & 1) * 8 + ((low >> 1) & 7);
        }
        const int l15 = tid & 15, e = (tid >> 4) & 7, lg = (tid >> 7) & 3;
        const int m = mt * 16 + l15;
        const int k = kt * 32 + lg * 8 + e;
        wsu[dst / 2 + (size_t)fid * 512 + (l15 + 16 * lg) * 8 + e] = f2bf(src[(size_t)k * ld + m]);
    } else {
        __shared__ int s_nz;
        __shared__ unsigned char s_v[256];
        const int mb = bid - 960;
        if (tid == 0) s_nz = 0;
        __syncthreads();
        int local = 0;
        if (tid < 256) {
            for (int j = 0; j < 64; j++) {
                const int i = tid * 64 + j;           // scan first 16KB
                if ((i & 3) != 0) local |= mraw[i];
            }
        }
        if (local) atomicOr(&s_nz, 1);
        __syncthreads();
        const bool isByte = (s_nz != 0);              // int32 0/1 LE: bytes i%4!=0 all 0
        if (tid < 256) {
            const int i = mb * 256 + tid;
            const unsigned char v = isByte ? (mraw[i] != 0) : (((const int*)mraw)[i] != 0);
            out2[i] = v ? 0.0f : 1.0f;
            s_v[tid] = v;
            if (v) { const int pos = atomicAdd(cnt, 1); list[pos] = (unsigned short)i; }
        }
        __syncthreads();
        const float4 z = {0.f, 0.f, 0.f, 0.f};
        for (int rr = 0; rr < 32; rr++) {
            const int row = rr * 8 + (tid >> 6);
            if (!s_v[row]) {
                const size_t go = (size_t)(mb * 256 + row) * 256;
                ((float4*)(out0 + go))[tid & 63] = z;
            }
        }
    }
}

// ---------------------------------------------------------------------------
// main encoder (active polylines only). 512 threads = 8 waves. [r13 verbatim]
// ---------------------------------------------------------------------------
__global__ __launch_bounds__(512, 4) void enc_mfma(
    const float* __restrict__ tgt, const int* __restrict__ label,
    const unsigned short* __restrict__ list, const int* __restrict__ cnt,
    const float* __restrict__ W1, const float* __restrict__ b1,
    const float* __restrict__ g1, const float* __restrict__ be1,
    const float* __restrict__ m1, const float* __restrict__ v1,
    const float* __restrict__ b2, const float* __restrict__ b3,
    const float* __restrict__ g2, const float* __restrict__ be2,
    const float* __restrict__ m2, const float* __restrict__ v2,
    const float* __restrict__ b4, const float* __restrict__ temb,
    const char* __restrict__ wsb, float* __restrict__ out0)
{
    extern __shared__ char smem[];
    const int nact  = cnt[0];
    const int bbase = blockIdx.x * NPB;
    if (bbase >= nact) return;

    const int tid  = threadIdx.x;
    const int wid  = tid >> 6;
    const int lane = tid & 63;
    const int l15  = lane & 15, lg = lane >> 4;

    // ---------- P0: feat (padded 36B rows, CAT overlay) + bn2 folded ------
    if (tid < NC) {
        const int c = tid, pl = c / 20, p = c - pl * 20;
        const int gpoly = list[min(bbase + pl, nact - 1)];
        const size_t gp = (size_t)gpoly * 42;
        const float px = tgt[gp + p * 2],     py = tgt[gp + p * 2 + 1];
        const float qx = tgt[gp + p * 2 + 2], qy = tgt[gp + p * 2 + 3];
        const float cx = tgt[gp + 20],        cy = tgt[gp + 21];
        const float vx = qx - px, vy = qy - py;
        const float inv = 1.0f / (sqrtf(vx * vx + vy * vy) + 1.0f + 1e-6f);
        float* f = (float*)(smem + L_CAT + c * 36);
        f[0] = px - cx; f[1] = py - cy; f[2] = vx; f[3] = vy;
        f[4] = vx * inv; f[5] = vy * inv;
    }
    if (tid < 256) {
        const float sc = rsqrtf(v2[tid] + 1e-5f) * g2[tid];
        ((float*)(smem + L_SC))[tid] = sc;
        ((float*)(smem + L_OF))[tid] = (b3[tid] - m2[tid]) * sc + be2[tid];
    }
    __syncthreads();

    // ---------- P1: h1 = relu(bn1(feat@W1+b1)) -> B-frags ----------
    {
        const int ch = tid & 127, cblk = tid >> 7;
        float w[6];
        #pragma unroll
        for (int j = 0; j < 6; j++) w[j] = W1[j * 128 + ch];
        const float sc1  = rsqrtf(v1[ch] + 1e-5f) * g1[ch];
        const float off1 = (b1[ch] - m1[ch]) * sc1 + be1[ch];
        const int kt = ch >> 5, koff = ch & 31;
        const int lane16 = 16 * (koff >> 3);
        #pragma unroll 4
        for (int i = 0; i < 20; i++) {
            const int c = i * 4 + cblk;
            const float* f = (const float*)(smem + L_CAT + c * 36);
            float a = 0.f;
            #pragma unroll
            for (int j = 0; j < 6; j++) a = fmaf(f[j], w[j], a);
            a = fmaxf(fmaf(a, sc1, off1), 0.0f);
            *(unsigned short*)(smem + L_H1 + (kt * NT + (c >> 4)) * 1024 +
                               ((c & 15) + lane16) * 16 + (koff & 7) * 2) = f2bf(a);
        }
    }
    __syncthreads();

    // ---------- S3: h^T = W2^T @ h1^T (M=256,N=80,K=128) ----------
    {
        bf16x8 a8[8];
        #pragma unroll
        for (int kt = 0; kt < 4; kt++) {
            #pragma unroll
            for (int mi = 0; mi < 2; mi++)
                a8[kt * 2 + mi] = *(const bf16x8*)(wsb + WS_W2 +
                    (size_t)(kt * 16 + wid * 2 + mi) * 1024 + lane * 16);
        }
        f32x4 acc[2][5];
        #pragma unroll
        for (int a = 0; a < 2; a++)
            #pragma unroll
            for (int b = 0; b < 5; b++) acc[a][b] = (f32x4){0.f, 0.f, 0.f, 0.f};

        __builtin_amdgcn_s_setprio(1);
        #pragma unroll
        for (int kt = 0; kt < 4; kt++) {
            #pragma unroll
            for (int nj = 0; nj < 5; nj++) {
                const bf16x8 bb = *(const bf16x8*)(smem + L_H1 + (kt * NT + nj) * 1024 + lane * 16);
                acc[0][nj] = __builtin_amdgcn_mfma_f32_16x16x32_bf16(a8[kt * 2 + 0], bb, acc[0][nj], 0, 0, 0);
                acc[1][nj] = __builtin_amdgcn_mfma_f32_16x16x32_bf16(a8[kt * 2 + 1], bb, acc[1][nj], 0, 0, 0);
            }
        }
        __builtin_amdgcn_s_setprio(0);
        #pragma unroll
        for (int mi = 0; mi < 2; mi++) {
            const int mt = wid * 2 + mi, chb = mt * 16 + lg * 4;
            const float4 bv = *(const float4*)(b2 + chb);
            const int kt = chb >> 5, koff = chb & 31;
            const int lane16 = l15 + 16 * (koff >> 3);
            #pragma unroll
            for (int nj = 0; nj < 5; nj++) {
                const f32x4 v = acc[mi][nj];
                uint2 pk;
                pk.x = cvtpk(v[0] + bv.x, v[1] + bv.y);
                pk.y = cvtpk(v[2] + bv.z, v[3] + bv.w);
                *(uint2*)(smem + L_CAT + (kt * NT + nj) * 1024 + lane16 * 16 + (koff & 7) * 2) = pk;
            }
        }
    }
    __syncthreads();

    // pooled-GEMM A-frags (W3 kt 8..15): issue loads NOW, hide under P3
    bf16x8 ap8[16];
    #pragma unroll
    for (int mi = 0; mi < 2; mi++) {
        const int mt = wid * 2 + mi;
        #pragma unroll
        for (int kk = 0; kk < 8; kk++) {
            const int kt = 8 + kk;
            const int fid = ((mt >> 2) * 4 + (kt >> 2)) * 16 + (mt & 3) * 4 + (kt & 3);
            ap8[mi * 8 + kk] = *(const bf16x8*)(wsb + WS_W3 + (size_t)fid * 1024 + lane * 16);
        }
    }

    // ---------- P3: pooled = max_p h, written directly as B-frags --------
    if (tid < 128) {
        const int pl = tid >> 5, grp = tid & 31;
        const int fragbase = (grp >> 2) * NT;
        const int off16 = 16 * (grp & 3);
        float mx[8];
        #pragma unroll
        for (int e = 0; e < 8; e++) mx[e] = -3.0e38f;
        #pragma unroll 4
        for (int p = 0; p < 20; p++) {
            int pp = p + grp;
            pp -= (pp >= 40) ? 40 : ((pp >= 20) ? 20 : 0);
            const int c = pl * 20 + pp;
            const uint4 v = *(const uint4*)(smem + L_CAT +
                (fragbase + (c >> 4)) * 1024 + ((c & 15) + off16) * 16);
            mx[0] = fmaxf(mx[0], bflo(v.x)); mx[1] = fmaxf(mx[1], bfhi(v.x));
            mx[2] = fmaxf(mx[2], bflo(v.y)); mx[3] = fmaxf(mx[3], bfhi(v.y));
            mx[4] = fmaxf(mx[4], bflo(v.z)); mx[5] = fmaxf(mx[5], bfhi(v.z));
            mx[6] = fmaxf(mx[6], bflo(v.w)); mx[7] = fmaxf(mx[7], bfhi(v.w));
        }
        uint4 pk;
        pk.x = cvtpk(mx[0], mx[1]); pk.y = cvtpk(mx[2], mx[3]);
        pk.z = cvtpk(mx[4], mx[5]); pk.w = cvtpk(mx[6], mx[7]);
        *(uint4*)(smem + L_PFRAG + (grp >> 2) * 1024 + (pl + 16 * (grp & 3)) * 16) = pk;
    }
    __syncthreads();

    // ---------- pooled GEMM: ap = pooled @ W3[256:]; APOF = ap*sc + OF ----
    {
        f32x4 accp0 = {0.f, 0.f, 0.f, 0.f}, accp1 = {0.f, 0.f, 0.f, 0.f};
        __builtin_amdgcn_s_setprio(1);
        #pragma unroll
        for (int kk = 0; kk < 8; kk++) {
            const bf16x8 bb = *(const bf16x8*)(smem + L_PFRAG + kk * 1024 + lane * 16);
            accp0 = __builtin_amdgcn_mfma_f32_16x16x32_bf16(ap8[kk],     bb, accp0, 0, 0, 0);
            accp1 = __builtin_amdgcn_mfma_f32_16x16x32_bf16(ap8[8 + kk], bb, accp1, 0, 0, 0);
        }
        __builtin_amdgcn_s_setprio(0);
        if (l15 < 4) {
            #pragma unroll
            for (int mi = 0; mi < 2; mi++) {
                const f32x4 v = mi ? accp1 : accp0;
                const int ch0 = (wid * 2 + mi) * 16 + lg * 4;
                const float4 scv = *(const float4*)(smem + L_SC + ch0 * 4);
                const float4 ofv = *(const float4*)(smem + L_OF + ch0 * 4);
                float4 o;
                o.x = fmaf(v[0], scv.x, ofv.x); o.y = fmaf(v[1], scv.y, ofv.y);
                o.z = fmaf(v[2], scv.z, ofv.z); o.w = fmaf(v[3], scv.w, ofv.w);
                *(float4*)(smem + L_APOF + l15 * 1024 + ch0 * 4) = o;
            }
        }
    }
    __syncthreads();

    unsigned abase[5];
    #pragma unroll
    for (int nj = 0; nj < 5; nj++)
        abase[5 > nj ? nj : 0] = L_APOF + (unsigned)((nj * 16 + l15) / 20) * 1024;

    // ---------- P4: 2 chunks of 128 out-ch: S4 (K=256) fused w/ S5 --------
    f32x4 acc5[5][2];
    #pragma unroll
    for (int a = 0; a < 5; a++) {
        acc5[a][0] = (f32x4){0.f, 0.f, 0.f, 0.f};
        acc5[a][1] = (f32x4){0.f, 0.f, 0.f, 0.f};
    }

    #pragma unroll 1
    for (int chunk = 0; chunk < 2; chunk++) {
        const int mtg = chunk * 8 + wid;
        bf16x8 a4[8];
        #pragma unroll
        for (int kk = 0; kk < 8; kk++) {
            const int fid = ((mtg >> 2) * 4 + (kk >> 2)) * 16 + (mtg & 3) * 4 + (kk & 3);
            a4[kk] = *(const bf16x8*)(wsb + WS_W3 + (size_t)fid * 1024 + lane * 16);
        }
        f32x4 acc4[5];
        #pragma unroll
        for (int s = 0; s < 5; s++) acc4[s] = (f32x4){0.f, 0.f, 0.f, 0.f};

        __builtin_amdgcn_s_setprio(1);
        #pragma unroll
        for (int ktg = 0; ktg < 8; ktg++) {
            #pragma unroll
            for (int nj = 0; nj < 5; nj++) {
                const bf16x8 bb = *(const bf16x8*)(smem + L_CAT + (ktg * NT + nj) * 1024 + lane * 16);
                acc4[nj] = __builtin_amdgcn_mfma_f32_16x16x32_bf16(a4[ktg], bb, acc4[nj], 0, 0, 0);
            }
        }
        __builtin_amdgcn_s_setprio(0);
        bf16x8 b5[8];
        #pragma unroll
        for (int kt2 = 0; kt2 < 4; kt2++) {
            #pragma unroll
            for (int njb = 0; njb < 2; njb++) {
                const int ktB = chunk * 4 + kt2, ntB = wid * 2 + njb;
                const int fid = (ktB >> 1) * 32 + ((ntB >> 3) & 1) * 16 + (ntB & 7) * 2 + (ktB & 1);
                b5[kt2 * 2 + njb] = *(const bf16x8*)(wsb + WS_W4 + (size_t)fid * 1024 + lane * 16);
            }
        }
        {
            const int choff = wid * 16 + lg * 4;
            const int ch0 = mtg * 16 + lg * 4;
            const float4 scv = *(const float4*)(smem + L_SC + ch0 * 4);
            const int kt2 = choff >> 5;
            const int lane16 = l15 + 16 * ((choff & 31) >> 3);
            const int sub = (lg & 1) * 8;
            #pragma unroll
            for (int nj = 0; nj < 5; nj++) {
                const float4 ofv = *(const float4*)(smem + abase[nj] + ch0 * 4);
                const f32x4 v = acc4[nj];
                uint2 pk;
                pk.x = cvtpk(fmaxf(fmaf(v[0], scv.x, ofv.x), 0.f),
                             fmaxf(fmaf(v[1], scv.y, ofv.y), 0.f));
                pk.y = cvtpk(fmaxf(fmaf(v[2], scv.z, ofv.z), 0.f),
                             fmaxf(fmaf(v[3], scv.w, ofv.w), 0.f));
                *(uint2*)(smem + L_H2C + (nj * 4 + kt2) * 1024 + lane16 * 16 + sub) = pk;
            }
        }
        __syncthreads();

        __builtin_amdgcn_s_setprio(1);
        #pragma unroll
        for (int kt2 = 0; kt2 < 4; kt2++) {
            #pragma unroll
            for (int mi = 0; mi < 5; mi++) {
                const bf16x8 a = *(const bf16x8*)(smem + L_H2C + (mi * 4 + kt2) * 1024 + lane * 16);
                acc5[mi][0] = __builtin_amdgcn_mfma_f32_16x16x32_bf16(a, b5[kt2 * 2 + 0], acc5[mi][0], 0, 0, 0);
                acc5[mi][1] = __builtin_amdgcn_mfma_f32_16x16x32_bf16(a, b5[kt2 * 2 + 1], acc5[mi][1], 0, 0, 0);
            }
        }
        __builtin_amdgcn_s_setprio(0);
        __syncthreads();
    }

    // ---------- P5: 4-col run maxes -> CAT overlay ----------
    #pragma unroll
    for (int mi = 0; mi < 5; mi++) {
        const int run = mi * 4 + lg;
        #pragma unroll
        for (int njb = 0; njb < 2; njb++) {
            const int ch = (wid * 2 + njb) * 16 + l15;
            const f32x4 v = acc5[mi][njb];
            const float m4 = fmaxf(fmaxf(v[0], v[1]), fmaxf(v[2], v[3]));
            *(unsigned short*)(smem + L_CAT + run * 512 + ch * 2) = f2bf(m4);
        }
    }
    __syncthreads();

    // ---------- P6: final max + b4 + type_emb ----------
    #pragma unroll
    for (int i = 0; i < 2; i++) {
        const int idx = i * 512 + tid, pl = idx >> 8, ch = idx & 255;
        if (bbase + pl < nact) {
            const int gpoly = list[bbase + pl];
            float mx = -3.0e38f;
            #pragma unroll
            for (int j = 0; j < 5; j++)
                mx = fmaxf(mx, bf2f(*(const unsigned short*)(smem + L_CAT +
                        (pl * 5 + j) * 512 + ch * 2)));
            out0[(size_t)gpoly * 256 + ch] = mx + b4[ch] + temb[label[gpoly] * 256 + ch];
        }
    }
}

// ---------------------------------------------------------------------------
// PE: r7/r13 byte-exact proven version (FROZEN). 32 rows/block x 512 blocks,
// identity row mapping, out2-masked writes.
// ---------------------------------------------------------------------------
#define PR     32
#define P_SINE 0          // 16 frags (kt0..7 x nt0..1)  16384
#define P_PHC  16384      // 32 frags (mt0..1 x kt0..15) 32768

__global__ __launch_bounds__(512, 4) void pe_mfma(
    const float* __restrict__ tgt, const float* __restrict__ out2,
    const float* __restrict__ bp1, const float* __restrict__ bp2,
    const float* __restrict__ pcr, const char* __restrict__ wsb,
    float* __restrict__ out1)
{
    __shared__ __align__(16) char sm[49152];
    const int tid  = threadIdx.x;
    const int wid  = tid >> 6;
    const int lane = tid & 63;
    const int l15  = lane & 15, lg = lane >> 4;
    const int base = blockIdx.x * PR;

    const float lox = pcr[0], loy = pcr[1];
    const float sx = 1.0f / (pcr[3] - pcr[0]), sy = 1.0f / (pcr[4] - pcr[1]);

    // sine B-frags: 1024 slots, 2 per thread
    #pragma unroll
    for (int i = 0; i < 2; i++) {
        const int u = i * 512 + tid;
        const int kt = u >> 7, nt = (u >> 6) & 1, s = u & 63;
        const int row = nt * 16 + (s & 15);
        const int lgs = s >> 4;
        const size_t gp = (size_t)(base + row) * 42;
        const float posx = (tgt[gp + 20] - lox) * sx;
        const float posy = (tgt[gp + 21] - loy) * sy;
        float fv[8];
        #pragma unroll
        for (int e = 0; e < 8; e++) {
            const int ch = kt * 32 + lgs * 8 + e;
            const float pos = (ch < 128) ? posy : posx;
            const int j7 = ch & 127, fi = j7 >> 1;
            const float freq = exp2f(-(float)fi * 0.20762050593046f) * 6.283185307179586f;
            const float arg = pos * freq;
            fv[e] = (j7 & 1) ? __cosf(arg) : __sinf(arg);
        }
        uint4 pk;
        pk.x = cvtpk(fv[0], fv[1]); pk.y = cvtpk(fv[2], fv[3]);
        pk.z = cvtpk(fv[4], fv[5]); pk.w = cvtpk(fv[6], fv[7]);
        *(uint4*)(sm + P_SINE + (kt * 2 + nt) * 1024 + s * 16) = pk;
    }
    __syncthreads();

    const int mw = wid >> 1, nw = wid & 1;

    f32x4 acc5[2][2];
    acc5[0][0] = (f32x4){0.f,0.f,0.f,0.f}; acc5[0][1] = (f32x4){0.f,0.f,0.f,0.f};
    acc5[1][0] = (f32x4){0.f,0.f,0.f,0.f}; acc5[1][1] = (f32x4){0.f,0.f,0.f,0.f};

    #pragma unroll 1
    for (int chunk = 0; chunk < 8; chunk++) {
        const int mt1 = chunk * 4 + mw;
        // prefetch all 8 Wp1 A-frags
        bf16x8 a8[8];
        #pragma unroll
        for (int kk = 0; kk < 8; kk++) {
            const int fid = ((mt1 >> 2) * 2 + (kk >> 2)) * 16 + (mt1 & 3) * 4 + (kk & 3);
            a8[kk] = *(const bf16x8*)(wsb + WS_WP1 + (size_t)fid * 1024 + lane * 16);
        }
        f32x4 acc4 = {0.f, 0.f, 0.f, 0.f};
        __builtin_amdgcn_s_setprio(1);
        #pragma unroll
        for (int kk = 0; kk < 8; kk++) {
            const bf16x8 bb = *(const bf16x8*)(sm + P_SINE + (kk * 2 + nw) * 1024 + lane * 16);
            acc4 = __builtin_amdgcn_mfma_f32_16x16x32_bf16(a8[kk], bb, acc4, 0, 0, 0);
        }
        __builtin_amdgcn_s_setprio(0);
        // issue GEMM2 B-frags (Wp2) for this chunk
        bf16x8 b5[4];
        #pragma unroll
        for (int kj = 0; kj < 2; kj++) {
            #pragma unroll
            for (int njj = 0; njj < 2; njj++) {
                const int ktB = chunk * 2 + kj, ntB = wid * 2 + njj;
                const int fid = (ktB >> 1) * 32 + ((ntB >> 3) & 1) * 16 + (ntB & 7) * 2 + (ktB & 1);
                b5[kj * 2 + njj] = *(const bf16x8*)(wsb + WS_WP2 + (size_t)fid * 1024 + lane * 16);
            }
        }
        // epilogue: + bp1, relu -> PHC A-frags
        {
            const int ch0 = mt1 * 16 + lg * 4;
            const float4 bv = *(const float4*)(bp1 + ch0);
            const int ktA = mt1 >> 1;
            const int slot = l15 + 16 * ((mt1 & 1) * 2 + (lg >> 1));
            uint2 pk;
            pk.x = cvtpk(fmaxf(acc4[0] + bv.x, 0.f), fmaxf(acc4[1] + bv.y, 0.f));
            pk.y = cvtpk(fmaxf(acc4[2] + bv.z, 0.f), fmaxf(acc4[3] + bv.w, 0.f));
            *(uint2*)(sm + P_PHC + (nw * 16 + ktA) * 1024 + slot * 16 + (lg & 1) * 8) = pk;
        }
        __syncthreads();
        // GEMM2: acc5 += phc @ Wp2[chunk]
        __builtin_amdgcn_s_setprio(1);
        #pragma unroll
        for (int kj = 0; kj < 2; kj++) {
            bf16x8 a[2];
            a[0] = *(const bf16x8*)(sm + P_PHC + (0 * 16 + chunk * 2 + kj) * 1024 + lane * 16);
            a[1] = *(const bf16x8*)(sm + P_PHC + (1 * 16 + chunk * 2 + kj) * 1024 + lane * 16);
            #pragma unroll
            for (int njj = 0; njj < 2; njj++) {
                acc5[0][njj] = __builtin_amdgcn_mfma_f32_16x16x32_bf16(a[0], b5[kj * 2 + njj], acc5[0][njj], 0, 0, 0);
                acc5[1][njj] = __builtin_amdgcn_mfma_f32_16x16x32_bf16(a[1], b5[kj * 2 + njj], acc5[1][njj], 0, 0, 0);
            }
        }
        __builtin_amdgcn_s_setprio(0);
        __syncthreads();
    }

    // final: +bp2, masked
    #pragma unroll
    for (int mi = 0; mi < 2; mi++) {
        #pragma unroll
        for (int njj = 0; njj < 2; njj++) {
            const int ch = (wid * 2 + njj) * 16 + l15;
            const float bo = bp2[ch];
            const f32x4 v = acc5[mi][njj];
            #pragma unroll
            for (int r = 0; r < 4; r++) {
                const int row = base + mi * 16 + lg * 4 + r;
                out1[(size_t)row * 256 + ch] = (out2[row] == 0.0f) ? (v[r] + bo) : 0.f;
            }
        }
    }
}

extern "C" void kernel_launch(void* const* d_in, const int* in_sizes, int n_in,
                              void* d_out, int out_size, void* d_ws, size_t ws_size,
                              hipStream_t stream) {
    const float*         tgt   = (const float*)d_in[0];
    const int*           lab   = (const int*)d_in[1];
    const unsigned char* mraw  = (const unsigned char*)d_in[2];
    const float* W1  = (const float*)d_in[3];
    const float* b1  = (const float*)d_in[4];
    const float* g1  = (const float*)d_in[5];
    const float* be1 = (const float*)d_in[6];
    const float* m1  = (const float*)d_in[7];
    const float* v1  = (const float*)d_in[8];
    const float* W2  = (const float*)d_in[9];
    const float* b2  = (const float*)d_in[10];
    const float* W3  = (const float*)d_in[11];
    const float* b3  = (const float*)d_in[12];
    const float* g2  = (const float*)d_in[13];
    const float* be2 = (const float*)d_in[14];
    const float* m2  = (const float*)d_in[15];
    const float* v2  = (const float*)d_in[16];
    const float* W4  = (const float*)d_in[17];
    const float* b4  = (const float*)d_in[18];
    const float* temb = (const float*)d_in[19];
    const float* Wp1 = (const float*)d_in[20];
    const float* bp1 = (const float*)d_in[21];
    const float* Wp2 = (const float*)d_in[22];
    const float* bp2 = (const float*)d_in[23];
    const float* pcr = (const float*)d_in[24];

    float* out0 = (float*)d_out;
    float* out1 = out0 + (size_t)NPOLY * 256;
    float* out2 = out1 + (size_t)NPOLY * 256;

    char*           wsb  = (char*)d_ws;
    int*            cnt  = (int*)(wsb + WS_CNT);
    unsigned short* list = (unsigned short*)(wsb + WS_LIST);
    unsigned short* wsu  = (unsigned short*)d_ws;

    hipFuncSetAttribute(reinterpret_cast<const void*>(enc_mfma),
                        hipFuncAttributeMaxDynamicSharedMemorySize, L_TOT);

    hipMemsetAsync(cnt, 0, 4, stream);
    prep_all<<<1024, 512, 0, stream>>>(W2, W3, W4, Wp1, Wp2, mraw,
                                       wsu, out2, list, cnt, out0);
    enc_mfma<<<NPOLY / NPB, 512, L_TOT, stream>>>(
        tgt, lab, list, cnt, W1, b1, g1, be1, m1, v1, b2, b3, g2, be2, m2, v2,
        b4, temb, wsb, out0);
    pe_mfma<<<NPOLY / PR, 512, 0, stream>>>(tgt, out2, bp1, bp2, pcr, wsb, out1);
}